// Round 1
// baseline (183.032 us; speedup 1.0000x reference)
//
#include <hip/hip_runtime.h>
#include <math.h>

#define KSIZE 31
#define HRAD 15

// ---------------------------------------------------------------------------
// Cube-map coordinate math (mirrors reference cube_sample exactly, f32)
// ---------------------------------------------------------------------------
__device__ inline void cube_coords(float x, float y, float z,
                                   int& face, float& u, float& v) {
    float ax = fabsf(x), ay = fabsf(y), az = fabsf(z);
    bool is_x = (ax >= ay) && (ax >= az);
    bool is_y = (!is_x) && (ay >= az);
    float ma, sc, tc;
    if (is_x) {
        if (x >= 0.0f) { face = 0; sc = -z; } else { face = 1; sc = z; }
        ma = ax; tc = -y;
    } else if (is_y) {
        if (y >= 0.0f) { face = 2; tc = z; } else { face = 3; tc = -z; }
        ma = ay; sc = x;
    } else {
        if (z >= 0.0f) { face = 4; sc = x; } else { face = 5; sc = -x; }
        ma = az; tc = -y;
    }
    float inv = 1.0f / fmaxf(ma, 1e-12f);
    u = 0.5f * (sc * inv + 1.0f);
    v = 0.5f * (tc * inv + 1.0f);
}

struct BL {
    int i00, i10, i01, i11;   // element index (already *3 for channel 0)
    float wx, wy;
};

__device__ inline BL bilinear_setup(float u, float v, int H, int W, int face) {
    float fx = u * (float)W - 0.5f;
    float fy = v * (float)H - 0.5f;
    float x0 = floorf(fx), y0 = floorf(fy);
    BL b;
    b.wx = fx - x0;
    b.wy = fy - y0;
    int x0i = min(max((int)x0, 0), W - 1);
    int x1i = min(max((int)x0 + 1, 0), W - 1);
    int y0i = min(max((int)y0, 0), H - 1);
    int y1i = min(max((int)y0 + 1, 0), H - 1);
    int base = face * H * W;
    b.i00 = (base + y0i * W + x0i) * 3;
    b.i10 = (base + y0i * W + x1i) * 3;
    b.i01 = (base + y1i * W + x0i) * 3;
    b.i11 = (base + y1i * W + x1i) * 3;
    return b;
}

__device__ inline void bilinear_fetch(const float* __restrict__ tex,
                                      const BL& b, float out[3]) {
    float wx = b.wx, wy = b.wy;
#pragma unroll
    for (int c = 0; c < 3; ++c) {
        float t00 = tex[b.i00 + c];
        float t10 = tex[b.i10 + c];
        float t01 = tex[b.i01 + c];
        float t11 = tex[b.i11 + c];
        out[c] = (t00 * (1.0f - wx) + t10 * wx) * (1.0f - wy) +
                 (t01 * (1.0f - wx) + t11 * wx) * wy;
    }
}

// ---------------------------------------------------------------------------
// Gaussian weights (computed per-block in double, matches numpy f64 path)
// ---------------------------------------------------------------------------
__device__ inline void compute_weights(int lvl, float* wS) {
    const int stds[4] = {8, 4, 2, 1};
    if (threadIdx.x == 0) {
        double s = (double)stds[lvl];
        double g[KSIZE];
        double sum = 0.0;
        for (int t = 0; t < KSIZE; ++t) {
            double d = (double)t - (double)HRAD;
            g[t] = exp(-0.5 * (d / s) * (d / s));
            sum += g[t];
        }
        for (int t = 0; t < KSIZE; ++t) wS[t] = (float)(g[t] / sum);
    }
}

// ---------------------------------------------------------------------------
// Separable blur: horizontal pass. block = 128 threads (one per x).
// blockIdx.x = (lvl*6 + face)*128 + yrow  -> 4*6*128 = 3072 blocks
// ---------------------------------------------------------------------------
__global__ __launch_bounds__(128)
void blur_h(const float* __restrict__ bg0, float* __restrict__ tmp) {
    __shared__ float wS[KSIZE];
    __shared__ float row[128 * 3];
    int bid  = blockIdx.x;
    int yrow = bid & 127;
    int face = (bid >> 7) % 6;
    int lvl  = bid / (6 * 128);
    int tid  = threadIdx.x;

    compute_weights(lvl, wS);

    const float* src = bg0 + (size_t)(face * 128 + yrow) * 128 * 3;
    for (int k = tid; k < 128 * 3; k += 128) row[k] = src[k];
    __syncthreads();

    int x = tid;
    float acc0 = 0.f, acc1 = 0.f, acc2 = 0.f;
    for (int t = 0; t < KSIZE; ++t) {
        int xx = x + t - HRAD;
        if (xx >= 0 && xx < 128) {
            float w = wS[t];
            acc0 += w * row[xx * 3 + 0];
            acc1 += w * row[xx * 3 + 1];
            acc2 += w * row[xx * 3 + 2];
        }
    }
    float* dst = tmp + ((size_t)((lvl * 6 + face) * 128 + yrow) * 128 + x) * 3;
    dst[0] = acc0; dst[1] = acc1; dst[2] = acc2;
}

// ---------------------------------------------------------------------------
// Separable blur: vertical pass. Same block mapping; reads are coalesced
// across x for each tap row.
// ---------------------------------------------------------------------------
__global__ __launch_bounds__(128)
void blur_v(const float* __restrict__ tmp, float* __restrict__ blurred) {
    __shared__ float wS[KSIZE];
    int bid  = blockIdx.x;
    int yrow = bid & 127;
    int face = (bid >> 7) % 6;
    int lvl  = bid / (6 * 128);

    compute_weights(lvl, wS);
    __syncthreads();

    int x = threadIdx.x;
    const float* base = tmp + (size_t)(lvl * 6 + face) * 128 * 128 * 3;
    float acc0 = 0.f, acc1 = 0.f, acc2 = 0.f;
    for (int t = 0; t < KSIZE; ++t) {
        int yy = yrow + t - HRAD;
        if (yy >= 0 && yy < 128) {
            float w = wS[t];
            const float* p = base + (size_t)(yy * 128 + x) * 3;
            acc0 += w * p[0];
            acc1 += w * p[1];
            acc2 += w * p[2];
        }
    }
    float* dst = blurred + ((size_t)((lvl * 6 + face) * 128 + yrow) * 128 + x) * 3;
    dst[0] = acc0; dst[1] = acc1; dst[2] = acc2;
}

// ---------------------------------------------------------------------------
// Per-sample shade kernel
// ---------------------------------------------------------------------------
__global__ __launch_bounds__(256)
void shade(const float* __restrict__ vd, const float* __restrict__ saS,
           const float* __restrict__ bg0, const float* __restrict__ bg1,
           const float* __restrict__ blurred, float* __restrict__ out, int B) {
    int i = blockIdx.x * blockDim.x + threadIdx.x;
    if (i >= B) return;

    float x = vd[3 * i + 0];
    float y = vd[3 * i + 1];
    float z = vd[3 * i + 2];
    int face; float u, v;
    cube_coords(x, y, z, face, u, v);

    // miplevel — mirror numpy f32 op order exactly
    const float saTexel = (float)(4.0 * M_PI / (6.0 * 512.0 * 512.0));
    float m = logf(saS[i] / saTexel);
    m = m / 1.3862943611198906f;   // f32(log(4))
    m = m * 0.5f;                  // /2.0 (exact)
    m = fminf(fmaxf(m, 0.0f), 3.0f);

    float r0, r1, r2;
    if (m >= 2.0f) {
        BL b = bilinear_setup(u, v, 128, 128, face);
        float blur0 = 0.f, blur1 = 0.f, blur2 = 0.f, wsum = 0.f;
        const float mips[4] = {3.0f, 2.5f, 2.0f, 1.5f};
#pragma unroll
        for (int l = 0; l < 4; ++l) {
            float w = 1.0f - fminf(fabsf(mips[l] - m), 1.0f);
            if (w > 0.0f) {
                float c[3];
                bilinear_fetch(blurred + (size_t)l * 6 * 128 * 128 * 3, b, c);
                blur0 += w * c[0];
                blur1 += w * c[1];
                blur2 += w * c[2];
                wsum += w;
            }
        }
        float denom = fmaxf(wsum, 1e-8f);
        r0 = blur0 / denom; r1 = blur1 / denom; r2 = blur2 / denom;
    } else {
        BL b0 = bilinear_setup(u, v, 128, 128, face);
        BL b1 = bilinear_setup(u, v, 512, 512, face);
        float c0[3], c1[3];
        bilinear_fetch(bg0, b0, c0);
        bilinear_fetch(bg1, b1, c1);
        r0 = c0[0] + 0.5f * c1[0];
        r1 = c0[1] + 0.5f * c1[1];
        r2 = c0[2] + 0.5f * c1[2];
    }
    out[3 * i + 0] = r0;
    out[3 * i + 1] = r1;
    out[3 * i + 2] = r2;
}

// ---------------------------------------------------------------------------
extern "C" void kernel_launch(void* const* d_in, const int* in_sizes, int n_in,
                              void* d_out, int out_size, void* d_ws, size_t ws_size,
                              hipStream_t stream) {
    const float* viewdirs = (const float*)d_in[0];   // (B,3)
    const float* saSample = (const float*)d_in[1];   // (B,1)
    const float* bg0      = (const float*)d_in[2];   // (6,128,128,3)
    const float* bg1      = (const float*)d_in[3];   // (6,512,512,3)
    float* out = (float*)d_out;

    int B = in_sizes[0] / 3;

    const size_t FACE_ELEMS = (size_t)6 * 128 * 128 * 3;   // 294912
    float* tmp     = (float*)d_ws;                 // 4 * FACE_ELEMS floats
    float* blurred = tmp + 4 * FACE_ELEMS;         // 4 * FACE_ELEMS floats

    blur_h<<<4 * 6 * 128, 128, 0, stream>>>(bg0, tmp);
    blur_v<<<4 * 6 * 128, 128, 0, stream>>>(tmp, blurred);

    int threads = 256;
    int blocks = (B + threads - 1) / threads;
    shade<<<blocks, threads, 0, stream>>>(viewdirs, saSample, bg0, bg1,
                                          blurred, out, B);
}

// Round 2
// 154.826 us; speedup vs baseline: 1.1822x; 1.1822x over previous
//
#include <hip/hip_runtime.h>
#include <hip/hip_fp16.h>
#include <math.h>

#define KSIZE 31
#define HRAD 15

// ---------------------------------------------------------------------------
// Cube-map coordinate math (mirrors reference cube_sample exactly, f32)
// ---------------------------------------------------------------------------
__device__ inline void cube_coords(float x, float y, float z,
                                   int& face, float& u, float& v) {
    float ax = fabsf(x), ay = fabsf(y), az = fabsf(z);
    bool is_x = (ax >= ay) && (ax >= az);
    bool is_y = (!is_x) && (ay >= az);
    float ma, sc, tc;
    if (is_x) {
        if (x >= 0.0f) { face = 0; sc = -z; } else { face = 1; sc = z; }
        ma = ax; tc = -y;
    } else if (is_y) {
        if (y >= 0.0f) { face = 2; tc = z; } else { face = 3; tc = -z; }
        ma = ay; sc = x;
    } else {
        if (z >= 0.0f) { face = 4; sc = x; } else { face = 5; sc = -x; }
        ma = az; tc = -y;
    }
    float inv = 1.0f / fmaxf(ma, 1e-12f);
    u = 0.5f * (sc * inv + 1.0f);
    v = 0.5f * (tc * inv + 1.0f);
}

// Tiled packed-texel index: texel (face,y,x) of an HxW map lives at
// float2 element ((face*H/2 + y/2)*W + x)*2 + (y&1).
// A 64B line thus holds a 4x2 (x-by-y) block of 8B half4 texels.
struct BLT {
    int i00, i10, i01, i11;
    float wx, wy;
};

__device__ inline BLT bl_tiled(float u, float v, int H, int W, int face) {
    float fx = u * (float)W - 0.5f;
    float fy = v * (float)H - 0.5f;
    float x0 = floorf(fx), y0 = floorf(fy);
    BLT b;
    b.wx = fx - x0;
    b.wy = fy - y0;
    int x0i = min(max((int)x0, 0), W - 1);
    int x1i = min(max((int)x0 + 1, 0), W - 1);
    int y0i = min(max((int)y0, 0), H - 1);
    int y1i = min(max((int)y0 + 1, 0), H - 1);
    int fb = face * (H >> 1);
    int r0 = (fb + (y0i >> 1)) * W;
    int r1 = (fb + (y1i >> 1)) * W;
    b.i00 = (r0 + x0i) * 2 + (y0i & 1);
    b.i10 = (r0 + x1i) * 2 + (y0i & 1);
    b.i01 = (r1 + x0i) * 2 + (y1i & 1);
    b.i11 = (r1 + x1i) * 2 + (y1i & 1);
    return b;
}

union H4U { float2 f2; __half h[4]; };

__device__ inline void fetch_bl(const float2* __restrict__ tex,
                                const BLT& b, float c[3]) {
    H4U t00, t10, t01, t11;
    t00.f2 = tex[b.i00];
    t10.f2 = tex[b.i10];
    t01.f2 = tex[b.i01];
    t11.f2 = tex[b.i11];
    float wx = b.wx, wy = b.wy;
#pragma unroll
    for (int k = 0; k < 3; ++k) {
        float top = __half2float(t00.h[k]) * (1.0f - wx) + __half2float(t10.h[k]) * wx;
        float bot = __half2float(t01.h[k]) * (1.0f - wx) + __half2float(t11.h[k]) * wx;
        c[k] = top * (1.0f - wy) + bot * wy;
    }
}

// ---------------------------------------------------------------------------
// Pack f32 RGB (face-major, row-major) -> half4 tiled layout
// nfaces may be 6 (bg maps) — treats input as nfaces maps of HxW.
// ---------------------------------------------------------------------------
__global__ __launch_bounds__(256)
void pack_tiled(const float* __restrict__ src, float2* __restrict__ dst,
                int H, int W, int total) {
    int i = blockIdx.x * blockDim.x + threadIdx.x;
    if (i >= total) return;
    int x = i % W;
    int y = (i / W) % H;
    int f = i / (W * H);
    H4U u;
    u.h[0] = __float2half(src[(size_t)i * 3 + 0]);
    u.h[1] = __float2half(src[(size_t)i * 3 + 1]);
    u.h[2] = __float2half(src[(size_t)i * 3 + 2]);
    u.h[3] = __float2half(0.0f);
    int idx = ((f * (H >> 1) + (y >> 1)) * W + x) * 2 + (y & 1);
    dst[idx] = u.f2;
}

// ---------------------------------------------------------------------------
// Gaussian weights (double precision, matches numpy f64 path)
// ---------------------------------------------------------------------------
__device__ inline void compute_weights(int lvl, float* wS) {
    const int stds[4] = {8, 4, 2, 1};
    if (threadIdx.x == 0) {
        double s = (double)stds[lvl];
        double g[KSIZE];
        double sum = 0.0;
        for (int t = 0; t < KSIZE; ++t) {
            double d = (double)t - (double)HRAD;
            g[t] = exp(-0.5 * (d / s) * (d / s));
            sum += g[t];
        }
        for (int t = 0; t < KSIZE; ++t) wS[t] = (float)(g[t] / sum);
    }
}

// ---------------------------------------------------------------------------
// Separable blur: horizontal pass (f32 out to tmp)
// blockIdx.x = (lvl*6 + face)*128 + yrow
// ---------------------------------------------------------------------------
__global__ __launch_bounds__(128)
void blur_h(const float* __restrict__ bg0, float* __restrict__ tmp) {
    __shared__ float wS[KSIZE];
    __shared__ float row[128 * 3];
    int bid  = blockIdx.x;
    int yrow = bid & 127;
    int face = (bid >> 7) % 6;
    int lvl  = bid / (6 * 128);
    int tid  = threadIdx.x;

    compute_weights(lvl, wS);

    const float* src = bg0 + (size_t)(face * 128 + yrow) * 128 * 3;
    for (int k = tid; k < 128 * 3; k += 128) row[k] = src[k];
    __syncthreads();

    int x = tid;
    float acc0 = 0.f, acc1 = 0.f, acc2 = 0.f;
    for (int t = 0; t < KSIZE; ++t) {
        int xx = x + t - HRAD;
        if (xx >= 0 && xx < 128) {
            float w = wS[t];
            acc0 += w * row[xx * 3 + 0];
            acc1 += w * row[xx * 3 + 1];
            acc2 += w * row[xx * 3 + 2];
        }
    }
    float* dst = tmp + ((size_t)((lvl * 6 + face) * 128 + yrow) * 128 + x) * 3;
    dst[0] = acc0; dst[1] = acc1; dst[2] = acc2;
}

// ---------------------------------------------------------------------------
// Separable blur: vertical pass, writes half4 tiled directly.
// Global face index = lvl*6 + face (24 maps of 128x128).
// ---------------------------------------------------------------------------
__global__ __launch_bounds__(128)
void blur_v_pack(const float* __restrict__ tmp, float2* __restrict__ blurp) {
    __shared__ float wS[KSIZE];
    int bid  = blockIdx.x;
    int yrow = bid & 127;
    int face = (bid >> 7) % 6;
    int lvl  = bid / (6 * 128);

    compute_weights(lvl, wS);
    __syncthreads();

    int x = threadIdx.x;
    const float* base = tmp + (size_t)(lvl * 6 + face) * 128 * 128 * 3;
    float acc0 = 0.f, acc1 = 0.f, acc2 = 0.f;
    for (int t = 0; t < KSIZE; ++t) {
        int yy = yrow + t - HRAD;
        if (yy >= 0 && yy < 128) {
            float w = wS[t];
            const float* p = base + (size_t)(yy * 128 + x) * 3;
            acc0 += w * p[0];
            acc1 += w * p[1];
            acc2 += w * p[2];
        }
    }
    H4U u;
    u.h[0] = __float2half(acc0);
    u.h[1] = __float2half(acc1);
    u.h[2] = __float2half(acc2);
    u.h[3] = __float2half(0.0f);
    int fg = lvl * 6 + face;
    int idx = ((fg * 64 + (yrow >> 1)) * 128 + x) * 2 + (yrow & 1);
    blurp[idx] = u.f2;
}

// ---------------------------------------------------------------------------
// Per-sample shade kernel (packed half4 tiled textures)
// ---------------------------------------------------------------------------
__global__ __launch_bounds__(256)
void shade(const float* __restrict__ vd, const float* __restrict__ saS,
           const float2* __restrict__ bg0p, const float2* __restrict__ bg1p,
           const float2* __restrict__ blurp, float* __restrict__ out, int B) {
    int i = blockIdx.x * blockDim.x + threadIdx.x;
    if (i >= B) return;

    float x = vd[3 * i + 0];
    float y = vd[3 * i + 1];
    float z = vd[3 * i + 2];
    int face; float u, v;
    cube_coords(x, y, z, face, u, v);

    // miplevel — mirror numpy f32 op order exactly
    const float saTexel = (float)(4.0 * M_PI / (6.0 * 512.0 * 512.0));
    float m = logf(saS[i] / saTexel);
    m = m / 1.3862943611198906f;   // f32(log(4))
    m = m * 0.5f;
    m = fminf(fmaxf(m, 0.0f), 3.0f);

    BLT b128 = bl_tiled(u, v, 128, 128, face);

    float r0, r1, r2;
    if (m >= 2.0f) {
        float blur0 = 0.f, blur1 = 0.f, blur2 = 0.f, wsum = 0.f;
        const float mips[4] = {3.0f, 2.5f, 2.0f, 1.5f};
#pragma unroll
        for (int l = 0; l < 4; ++l) {
            float w = 1.0f - fminf(fabsf(mips[l] - m), 1.0f);
            if (w > 0.0f) {
                float c[3];
                fetch_bl(blurp + (size_t)l * 6 * 64 * 128 * 2, b128, c);
                blur0 += w * c[0];
                blur1 += w * c[1];
                blur2 += w * c[2];
                wsum += w;
            }
        }
        float denom = fmaxf(wsum, 1e-8f);
        r0 = blur0 / denom; r1 = blur1 / denom; r2 = blur2 / denom;
    } else {
        BLT b512 = bl_tiled(u, v, 512, 512, face);
        float c0[3], c1[3];
        fetch_bl(bg0p, b128, c0);
        fetch_bl(bg1p, b512, c1);
        r0 = c0[0] + 0.5f * c1[0];
        r1 = c0[1] + 0.5f * c1[1];
        r2 = c0[2] + 0.5f * c1[2];
    }
    out[3 * i + 0] = r0;
    out[3 * i + 1] = r1;
    out[3 * i + 2] = r2;
}

// ---------------------------------------------------------------------------
extern "C" void kernel_launch(void* const* d_in, const int* in_sizes, int n_in,
                              void* d_out, int out_size, void* d_ws, size_t ws_size,
                              hipStream_t stream) {
    const float* viewdirs = (const float*)d_in[0];   // (B,3)
    const float* saSample = (const float*)d_in[1];   // (B,1)
    const float* bg0      = (const float*)d_in[2];   // (6,128,128,3)
    const float* bg1      = (const float*)d_in[3];   // (6,512,512,3)
    float* out = (float*)d_out;

    int B = in_sizes[0] / 3;

    // ws layout (float2 = 8B):
    //   blurp : 4*6*64*128*2  = 393216 float2  (3.1 MB)
    //   bg0p  : 6*64*128*2    =  98304 float2  (0.79 MB)
    //   bg1p  : 6*256*512*2   = 1572864 float2 (12.6 MB)
    //   tmp   : 4*6*128*128*3 = 1179648 float  (4.7 MB)
    float2* blurp = (float2*)d_ws;
    float2* bg0p  = blurp + 393216;
    float2* bg1p  = bg0p + 98304;
    float*  tmp   = (float*)(bg1p + 1572864);

    int t0 = 6 * 128 * 128;
    int t1 = 6 * 512 * 512;
    pack_tiled<<<(t0 + 255) / 256, 256, 0, stream>>>(bg0, bg0p, 128, 128, t0);
    pack_tiled<<<(t1 + 255) / 256, 256, 0, stream>>>(bg1, bg1p, 512, 512, t1);

    blur_h<<<4 * 6 * 128, 128, 0, stream>>>(bg0, tmp);
    blur_v_pack<<<4 * 6 * 128, 128, 0, stream>>>(tmp, blurp);

    int threads = 256;
    int blocks = (B + threads - 1) / threads;
    shade<<<blocks, threads, 0, stream>>>(viewdirs, saSample, bg0p, bg1p,
                                          blurp, out, B);
}

// Round 3
// 127.430 us; speedup vs baseline: 1.4363x; 1.2150x over previous
//
#include <hip/hip_runtime.h>
#include <hip/hip_fp16.h>
#include <math.h>

#define KSIZE 31
#define HRAD 15

// ---------------------------------------------------------------------------
// Cube-map coordinate math (mirrors reference cube_sample exactly, f32)
// ---------------------------------------------------------------------------
__device__ inline void cube_coords(float x, float y, float z,
                                   int& face, float& u, float& v) {
    float ax = fabsf(x), ay = fabsf(y), az = fabsf(z);
    bool is_x = (ax >= ay) && (ax >= az);
    bool is_y = (!is_x) && (ay >= az);
    float ma, sc, tc;
    if (is_x) {
        if (x >= 0.0f) { face = 0; sc = -z; } else { face = 1; sc = z; }
        ma = ax; tc = -y;
    } else if (is_y) {
        if (y >= 0.0f) { face = 2; tc = z; } else { face = 3; tc = -z; }
        ma = ay; sc = x;
    } else {
        if (z >= 0.0f) { face = 4; sc = x; } else { face = 5; sc = -x; }
        ma = az; tc = -y;
    }
    float inv = 1.0f / fmaxf(ma, 1e-12f);
    u = 0.5f * (sc * inv + 1.0f);
    v = 0.5f * (tc * inv + 1.0f);
}

// ---------------------------------------------------------------------------
// 8B half4 texels, 2-row-paired tiled layout (bg0p / bg1p):
// float2 element ((face*H/2 + y/2)*W + x)*2 + (y&1)
// ---------------------------------------------------------------------------
struct BLT {
    int i00, i10, i01, i11;
    float wx, wy;
};

__device__ inline BLT bl_tiled(float u, float v, int H, int W, int face) {
    float fx = u * (float)W - 0.5f;
    float fy = v * (float)H - 0.5f;
    float x0 = floorf(fx), y0 = floorf(fy);
    BLT b;
    b.wx = fx - x0;
    b.wy = fy - y0;
    int x0i = min(max((int)x0, 0), W - 1);
    int x1i = min(max((int)x0 + 1, 0), W - 1);
    int y0i = min(max((int)y0, 0), H - 1);
    int y1i = min(max((int)y0 + 1, 0), H - 1);
    int fb = face * (H >> 1);
    int r0 = (fb + (y0i >> 1)) * W;
    int r1 = (fb + (y1i >> 1)) * W;
    b.i00 = (r0 + x0i) * 2 + (y0i & 1);
    b.i10 = (r0 + x1i) * 2 + (y0i & 1);
    b.i01 = (r1 + x0i) * 2 + (y1i & 1);
    b.i11 = (r1 + x1i) * 2 + (y1i & 1);
    return b;
}

union H4U { float2 f2; __half h[4]; };
union H8U { float4 f4; __half h[8]; };

__device__ inline void fetch_bl(const float2* __restrict__ tex,
                                const BLT& b, float c[3]) {
    H4U t00, t10, t01, t11;
    t00.f2 = tex[b.i00];
    t10.f2 = tex[b.i10];
    t01.f2 = tex[b.i01];
    t11.f2 = tex[b.i11];
    float wx = b.wx, wy = b.wy;
#pragma unroll
    for (int k = 0; k < 3; ++k) {
        float top = __half2float(t00.h[k]) * (1.0f - wx) + __half2float(t10.h[k]) * wx;
        float bot = __half2float(t01.h[k]) * (1.0f - wx) + __half2float(t11.h[k]) * wx;
        c[k] = top * (1.0f - wy) + bot * wy;
    }
}

// ---------------------------------------------------------------------------
// Interleaved blur records: per 128-map texel, 4 levels x half4 = 32B.
// record index rec = ((face*64 + y/2)*128 + x)*2 + (y&1); bytes = rec*32.
// A 64B line = vertical texel pair (y0,y1 of same x).
// ---------------------------------------------------------------------------
struct BLR {
    int r00, r10, r01, r11;
    float wx, wy;
};

__device__ inline BLR bl_rec(float u, float v, int face) {
    float fx = u * 128.0f - 0.5f;
    float fy = v * 128.0f - 0.5f;
    float x0 = floorf(fx), y0 = floorf(fy);
    BLR b;
    b.wx = fx - x0;
    b.wy = fy - y0;
    int x0i = min(max((int)x0, 0), 127);
    int x1i = min(max((int)x0 + 1, 0), 127);
    int y0i = min(max((int)y0, 0), 127);
    int y1i = min(max((int)y0 + 1, 0), 127);
    int fb = face * 64;
    int r0 = (fb + (y0i >> 1)) * 128;
    int r1 = (fb + (y1i >> 1)) * 128;
    b.r00 = (r0 + x0i) * 2 + (y0i & 1);
    b.r10 = (r0 + x1i) * 2 + (y0i & 1);
    b.r01 = (r1 + x0i) * 2 + (y1i & 1);
    b.r11 = (r1 + x1i) * 2 + (y1i & 1);
    return b;
}

// accumulate one blur level (half index off = 0 or 4) into b0..b2
__device__ inline void accum_level(const H8U& q00, const H8U& q10,
                                   const H8U& q01, const H8U& q11,
                                   int off, float w, float wx, float wy,
                                   float& b0, float& b1, float& b2) {
    float c[3];
#pragma unroll
    for (int k = 0; k < 3; ++k) {
        float top = __half2float(q00.h[off + k]) * (1.0f - wx) + __half2float(q10.h[off + k]) * wx;
        float bot = __half2float(q01.h[off + k]) * (1.0f - wx) + __half2float(q11.h[off + k]) * wx;
        c[k] = top * (1.0f - wy) + bot * wy;
    }
    b0 += w * c[0];
    b1 += w * c[1];
    b2 += w * c[2];
}

// ---------------------------------------------------------------------------
// Pack f32 RGB (face-major, row-major) -> half4 tiled layout
// ---------------------------------------------------------------------------
__global__ __launch_bounds__(256)
void pack_tiled(const float* __restrict__ src, float2* __restrict__ dst,
                int H, int W, int total) {
    int i = blockIdx.x * blockDim.x + threadIdx.x;
    if (i >= total) return;
    int x = i % W;
    int y = (i / W) % H;
    int f = i / (W * H);
    H4U u;
    u.h[0] = __float2half(src[(size_t)i * 3 + 0]);
    u.h[1] = __float2half(src[(size_t)i * 3 + 1]);
    u.h[2] = __float2half(src[(size_t)i * 3 + 2]);
    u.h[3] = __float2half(0.0f);
    int idx = ((f * (H >> 1) + (y >> 1)) * W + x) * 2 + (y & 1);
    dst[idx] = u.f2;
}

// ---------------------------------------------------------------------------
// Weight table: 4 levels x 31 taps (stride 32), computed ONCE.
// One f64 exp per thread, parallel — no per-block serial f64 section.
// ---------------------------------------------------------------------------
__global__ __launch_bounds__(128)
void init_weights(float* __restrict__ wts) {
    __shared__ double gs[4][32];
    __shared__ double sums[4];
    int lvl = threadIdx.x >> 5;
    int t   = threadIdx.x & 31;
    const int stds[4] = {8, 4, 2, 1};
    double g = 0.0;
    if (t < KSIZE) {
        double d = (double)t - 15.0;
        double s = (double)stds[lvl];
        g = exp(-0.5 * (d / s) * (d / s));
    }
    gs[lvl][t] = g;
    __syncthreads();
    if (t == 0) {
        double sum = 0.0;
        for (int k = 0; k < KSIZE; ++k) sum += gs[lvl][k];
        sums[lvl] = sum;
    }
    __syncthreads();
    wts[lvl * 32 + t] = (t < KSIZE) ? (float)(g / sums[lvl]) : 0.0f;
}

// ---------------------------------------------------------------------------
// Horizontal blur, all 4 levels per block. blockIdx = face*128 + yrow.
// ---------------------------------------------------------------------------
__global__ __launch_bounds__(128)
void blur_h4(const float* __restrict__ bg0, float* __restrict__ tmp,
             const float* __restrict__ wts) {
    __shared__ float wS[4][32];
    __shared__ float row[128 * 3];
    int bid  = blockIdx.x;
    int yrow = bid & 127;
    int face = bid >> 7;
    int tid  = threadIdx.x;

    wS[tid >> 5][tid & 31] = wts[tid];
    const float* src = bg0 + (size_t)(face * 128 + yrow) * 128 * 3;
    for (int k = tid; k < 128 * 3; k += 128) row[k] = src[k];
    __syncthreads();

    int x = tid;
#pragma unroll
    for (int lvl = 0; lvl < 4; ++lvl) {
        float a0 = 0.f, a1 = 0.f, a2 = 0.f;
        for (int t = 0; t < KSIZE; ++t) {
            int xx = x + t - HRAD;
            if (xx >= 0 && xx < 128) {
                float w = wS[lvl][t];
                a0 += w * row[xx * 3 + 0];
                a1 += w * row[xx * 3 + 1];
                a2 += w * row[xx * 3 + 2];
            }
        }
        float* dst = tmp + ((size_t)((lvl * 6 + face) * 128 + yrow) * 128 + x) * 3;
        dst[0] = a0; dst[1] = a1; dst[2] = a2;
    }
}

// ---------------------------------------------------------------------------
// Vertical blur, all 4 levels per block; writes one full 32B record
// (2 x float4, aligned) per texel.  blockIdx = face*128 + yrow.
// ---------------------------------------------------------------------------
__global__ __launch_bounds__(128)
void blur_v4(const float* __restrict__ tmp, float4* __restrict__ blurp,
             const float* __restrict__ wts) {
    __shared__ float wS[4][32];
    int bid  = blockIdx.x;
    int yrow = bid & 127;
    int face = bid >> 7;
    int tid  = threadIdx.x;

    wS[tid >> 5][tid & 31] = wts[tid];
    __syncthreads();

    int x = tid;
    H8U ra, rb;
#pragma unroll
    for (int lvl = 0; lvl < 4; ++lvl) {
        const float* base = tmp + (size_t)(lvl * 6 + face) * 128 * 128 * 3;
        float a0 = 0.f, a1 = 0.f, a2 = 0.f;
        for (int t = 0; t < KSIZE; ++t) {
            int yy = yrow + t - HRAD;
            if (yy >= 0 && yy < 128) {
                float w = wS[lvl][t];
                const float* p = base + (size_t)(yy * 128 + x) * 3;
                a0 += w * p[0];
                a1 += w * p[1];
                a2 += w * p[2];
            }
        }
        H8U& r = (lvl < 2) ? ra : rb;
        int off = (lvl & 1) * 4;
        r.h[off + 0] = __float2half(a0);
        r.h[off + 1] = __float2half(a1);
        r.h[off + 2] = __float2half(a2);
        r.h[off + 3] = __float2half(0.0f);
    }
    int rec = ((face * 64 + (yrow >> 1)) * 128 + x) * 2 + (yrow & 1);
    blurp[rec * 2 + 0] = ra.f4;
    blurp[rec * 2 + 1] = rb.f4;
}

// ---------------------------------------------------------------------------
// Per-sample shade kernel
// ---------------------------------------------------------------------------
__global__ __launch_bounds__(256)
void shade(const float* __restrict__ vd, const float* __restrict__ saS,
           const float2* __restrict__ bg0p, const float2* __restrict__ bg1p,
           const float4* __restrict__ blurp, float* __restrict__ out, int B) {
    int i = blockIdx.x * blockDim.x + threadIdx.x;
    if (i >= B) return;

    float x = vd[3 * i + 0];
    float y = vd[3 * i + 1];
    float z = vd[3 * i + 2];
    int face; float u, v;
    cube_coords(x, y, z, face, u, v);

    // miplevel — mirror numpy f32 op order exactly
    const float saTexel = (float)(4.0 * M_PI / (6.0 * 512.0 * 512.0));
    float m = logf(saS[i] / saTexel);
    m = m / 1.3862943611198906f;   // f32(log(4))
    m = m * 0.5f;
    m = fminf(fmaxf(m, 0.0f), 3.0f);

    float r0, r1, r2;
    if (m >= 2.0f) {
        BLR b = bl_rec(u, v, face);
        H8U q00a, q00b, q10a, q10b, q01a, q01b, q11a, q11b;
        q00a.f4 = blurp[b.r00 * 2 + 0]; q00b.f4 = blurp[b.r00 * 2 + 1];
        q10a.f4 = blurp[b.r10 * 2 + 0]; q10b.f4 = blurp[b.r10 * 2 + 1];
        q01a.f4 = blurp[b.r01 * 2 + 0]; q01b.f4 = blurp[b.r01 * 2 + 1];
        q11a.f4 = blurp[b.r11 * 2 + 0]; q11b.f4 = blurp[b.r11 * 2 + 1];

        float w0 = 1.0f - fminf(fabsf(3.0f - m), 1.0f);
        float w1 = 1.0f - fminf(fabsf(2.5f - m), 1.0f);
        float w2 = 1.0f - fminf(fabsf(2.0f - m), 1.0f);
        float w3 = 1.0f - fminf(fabsf(1.5f - m), 1.0f);

        float b0 = 0.f, b1 = 0.f, b2 = 0.f;
        accum_level(q00a, q10a, q01a, q11a, 0, w0, b.wx, b.wy, b0, b1, b2);
        accum_level(q00a, q10a, q01a, q11a, 4, w1, b.wx, b.wy, b0, b1, b2);
        accum_level(q00b, q10b, q01b, q11b, 0, w2, b.wx, b.wy, b0, b1, b2);
        accum_level(q00b, q10b, q01b, q11b, 4, w3, b.wx, b.wy, b0, b1, b2);

        float denom = fmaxf(w0 + w1 + w2 + w3, 1e-8f);
        r0 = b0 / denom; r1 = b1 / denom; r2 = b2 / denom;
    } else {
        BLT b128 = bl_tiled(u, v, 128, 128, face);
        BLT b512 = bl_tiled(u, v, 512, 512, face);
        float c0[3], c1[3];
        fetch_bl(bg0p, b128, c0);
        fetch_bl(bg1p, b512, c1);
        r0 = c0[0] + 0.5f * c1[0];
        r1 = c0[1] + 0.5f * c1[1];
        r2 = c0[2] + 0.5f * c1[2];
    }
    out[3 * i + 0] = r0;
    out[3 * i + 1] = r1;
    out[3 * i + 2] = r2;
}

// ---------------------------------------------------------------------------
extern "C" void kernel_launch(void* const* d_in, const int* in_sizes, int n_in,
                              void* d_out, int out_size, void* d_ws, size_t ws_size,
                              hipStream_t stream) {
    const float* viewdirs = (const float*)d_in[0];   // (B,3)
    const float* saSample = (const float*)d_in[1];   // (B,1)
    const float* bg0      = (const float*)d_in[2];   // (6,128,128,3)
    const float* bg1      = (const float*)d_in[3];   // (6,512,512,3)
    float* out = (float*)d_out;

    int B = in_sizes[0] / 3;

    // ws layout:
    //   blurp : 6*128*128 records * 32B = 196608 float4   (3.0 MB)
    //   bg0p  : 98304 float2                              (0.79 MB)
    //   bg1p  : 1572864 float2                            (12.6 MB)
    //   tmp   : 4*6*128*128*3 float                       (4.7 MB)
    //   wts   : 128 float
    float4* blurp = (float4*)d_ws;
    float2* bg0p  = (float2*)(blurp + 196608);
    float2* bg1p  = bg0p + 98304;
    float*  tmp   = (float*)(bg1p + 1572864);
    float*  wts   = tmp + 1179648;

    init_weights<<<1, 128, 0, stream>>>(wts);

    int t0 = 6 * 128 * 128;
    int t1 = 6 * 512 * 512;
    pack_tiled<<<(t0 + 255) / 256, 256, 0, stream>>>(bg0, bg0p, 128, 128, t0);
    pack_tiled<<<(t1 + 255) / 256, 256, 0, stream>>>(bg1, bg1p, 512, 512, t1);

    blur_h4<<<6 * 128, 128, 0, stream>>>(bg0, tmp, wts);
    blur_v4<<<6 * 128, 128, 0, stream>>>(tmp, blurp, wts);

    int threads = 256;
    int blocks = (B + threads - 1) / threads;
    shade<<<blocks, threads, 0, stream>>>(viewdirs, saSample, bg0p, bg1p,
                                          blurp, out, B);
}

// Round 4
// 126.627 us; speedup vs baseline: 1.4454x; 1.0063x over previous
//
#include <hip/hip_runtime.h>
#include <hip/hip_fp16.h>
#include <math.h>

#define KSIZE 31
#define HRAD 15

// ---------------------------------------------------------------------------
// Cube-map coordinate math (mirrors reference cube_sample exactly, f32)
// ---------------------------------------------------------------------------
__device__ inline void cube_coords(float x, float y, float z,
                                   int& face, float& u, float& v) {
    float ax = fabsf(x), ay = fabsf(y), az = fabsf(z);
    bool is_x = (ax >= ay) && (ax >= az);
    bool is_y = (!is_x) && (ay >= az);
    float ma, sc, tc;
    if (is_x) {
        if (x >= 0.0f) { face = 0; sc = -z; } else { face = 1; sc = z; }
        ma = ax; tc = -y;
    } else if (is_y) {
        if (y >= 0.0f) { face = 2; tc = z; } else { face = 3; tc = -z; }
        ma = ay; sc = x;
    } else {
        if (z >= 0.0f) { face = 4; sc = x; } else { face = 5; sc = -x; }
        ma = az; tc = -y;
    }
    float inv = 1.0f / fmaxf(ma, 1e-12f);
    u = 0.5f * (sc * inv + 1.0f);
    v = 0.5f * (tc * inv + 1.0f);
}

// ---------------------------------------------------------------------------
// 8B half4 texels, 2-row-paired tiled layout (bg0p / bg1p):
// float2 element ((face*H/2 + y/2)*W + x)*2 + (y&1)
// ---------------------------------------------------------------------------
struct BLT {
    int i00, i10, i01, i11;
    float wx, wy;
};

__device__ inline BLT bl_tiled(float u, float v, int H, int W, int face) {
    float fx = u * (float)W - 0.5f;
    float fy = v * (float)H - 0.5f;
    float x0 = floorf(fx), y0 = floorf(fy);
    BLT b;
    b.wx = fx - x0;
    b.wy = fy - y0;
    int x0i = min(max((int)x0, 0), W - 1);
    int x1i = min(max((int)x0 + 1, 0), W - 1);
    int y0i = min(max((int)y0, 0), H - 1);
    int y1i = min(max((int)y0 + 1, 0), H - 1);
    int fb = face * (H >> 1);
    int r0 = (fb + (y0i >> 1)) * W;
    int r1 = (fb + (y1i >> 1)) * W;
    b.i00 = (r0 + x0i) * 2 + (y0i & 1);
    b.i10 = (r0 + x1i) * 2 + (y0i & 1);
    b.i01 = (r1 + x0i) * 2 + (y1i & 1);
    b.i11 = (r1 + x1i) * 2 + (y1i & 1);
    return b;
}

union H4U { float2 f2; __half h[4]; };
union H8U { float4 f4; __half h[8]; };

__device__ inline void fetch_bl(const float2* __restrict__ tex,
                                const BLT& b, float c[3]) {
    H4U t00, t10, t01, t11;
    t00.f2 = tex[b.i00];
    t10.f2 = tex[b.i10];
    t01.f2 = tex[b.i01];
    t11.f2 = tex[b.i11];
    float wx = b.wx, wy = b.wy;
#pragma unroll
    for (int k = 0; k < 3; ++k) {
        float top = __half2float(t00.h[k]) * (1.0f - wx) + __half2float(t10.h[k]) * wx;
        float bot = __half2float(t01.h[k]) * (1.0f - wx) + __half2float(t11.h[k]) * wx;
        c[k] = top * (1.0f - wy) + bot * wy;
    }
}

// ---------------------------------------------------------------------------
// Interleaved blur records: per 128-map texel, 4 levels x half4 = 32B.
// record index rec = ((face*64 + y/2)*128 + x)*2 + (y&1)
// ---------------------------------------------------------------------------
struct BLR {
    int r00, r10, r01, r11;
    float wx, wy;
};

__device__ inline BLR bl_rec(float u, float v, int face) {
    float fx = u * 128.0f - 0.5f;
    float fy = v * 128.0f - 0.5f;
    float x0 = floorf(fx), y0 = floorf(fy);
    BLR b;
    b.wx = fx - x0;
    b.wy = fy - y0;
    int x0i = min(max((int)x0, 0), 127);
    int x1i = min(max((int)x0 + 1, 0), 127);
    int y0i = min(max((int)y0, 0), 127);
    int y1i = min(max((int)y0 + 1, 0), 127);
    int fb = face * 64;
    int r0 = (fb + (y0i >> 1)) * 128;
    int r1 = (fb + (y1i >> 1)) * 128;
    b.r00 = (r0 + x0i) * 2 + (y0i & 1);
    b.r10 = (r0 + x1i) * 2 + (y0i & 1);
    b.r01 = (r1 + x0i) * 2 + (y1i & 1);
    b.r11 = (r1 + x1i) * 2 + (y1i & 1);
    return b;
}

__device__ inline void accum_level(const H8U& q00, const H8U& q10,
                                   const H8U& q01, const H8U& q11,
                                   int off, float w, float wx, float wy,
                                   float& b0, float& b1, float& b2) {
    float c[3];
#pragma unroll
    for (int k = 0; k < 3; ++k) {
        float top = __half2float(q00.h[off + k]) * (1.0f - wx) + __half2float(q10.h[off + k]) * wx;
        float bot = __half2float(q01.h[off + k]) * (1.0f - wx) + __half2float(q11.h[off + k]) * wx;
        c[k] = top * (1.0f - wy) + bot * wy;
    }
    b0 += w * c[0];
    b1 += w * c[1];
    b2 += w * c[2];
}

// ---------------------------------------------------------------------------
// Pack f32 RGB (face-major, row-major) -> half4 tiled layout
// ---------------------------------------------------------------------------
__global__ __launch_bounds__(256)
void pack_tiled(const float* __restrict__ src, float2* __restrict__ dst,
                int H, int W, int total) {
    int i = blockIdx.x * blockDim.x + threadIdx.x;
    if (i >= total) return;
    int x = i % W;
    int y = (i / W) % H;
    int f = i / (W * H);
    H4U u;
    u.h[0] = __float2half(src[(size_t)i * 3 + 0]);
    u.h[1] = __float2half(src[(size_t)i * 3 + 1]);
    u.h[2] = __float2half(src[(size_t)i * 3 + 2]);
    u.h[3] = __float2half(0.0f);
    int idx = ((f * (H >> 1) + (y >> 1)) * W + x) * 2 + (y & 1);
    dst[idx] = u.f2;
}

// ---------------------------------------------------------------------------
// Weight table: 4 levels x 31 taps (stride 32), computed ONCE, in parallel.
// ---------------------------------------------------------------------------
__global__ __launch_bounds__(128)
void init_weights(float* __restrict__ wts) {
    __shared__ double gs[4][32];
    __shared__ double sums[4];
    int lvl = threadIdx.x >> 5;
    int t   = threadIdx.x & 31;
    const int stds[4] = {8, 4, 2, 1};
    double g = 0.0;
    if (t < KSIZE) {
        double d = (double)t - 15.0;
        double s = (double)stds[lvl];
        g = exp(-0.5 * (d / s) * (d / s));
    }
    gs[lvl][t] = g;
    __syncthreads();
    if (t == 0) {
        double sum = 0.0;
        for (int k = 0; k < KSIZE; ++k) sum += gs[lvl][k];
        sums[lvl] = sum;
    }
    __syncthreads();
    wts[lvl * 32 + t] = (t < KSIZE) ? (float)(g / sums[lvl]) : 0.0f;
}

// ---------------------------------------------------------------------------
// Horizontal blur, all 4 levels per block. blockIdx = face*128 + yrow.
// ---------------------------------------------------------------------------
__global__ __launch_bounds__(128)
void blur_h4(const float* __restrict__ bg0, float* __restrict__ tmp,
             const float* __restrict__ wts) {
    __shared__ float wS[4][32];
    __shared__ float row[128 * 3];
    int bid  = blockIdx.x;
    int yrow = bid & 127;
    int face = bid >> 7;
    int tid  = threadIdx.x;

    wS[tid >> 5][tid & 31] = wts[tid];
    const float* src = bg0 + (size_t)(face * 128 + yrow) * 128 * 3;
    for (int k = tid; k < 128 * 3; k += 128) row[k] = src[k];
    __syncthreads();

    int x = tid;
#pragma unroll
    for (int lvl = 0; lvl < 4; ++lvl) {
        float a0 = 0.f, a1 = 0.f, a2 = 0.f;
        for (int t = 0; t < KSIZE; ++t) {
            int xx = x + t - HRAD;
            if (xx >= 0 && xx < 128) {
                float w = wS[lvl][t];
                a0 += w * row[xx * 3 + 0];
                a1 += w * row[xx * 3 + 1];
                a2 += w * row[xx * 3 + 2];
            }
        }
        float* dst = tmp + ((size_t)((lvl * 6 + face) * 128 + yrow) * 128 + x) * 3;
        dst[0] = a0; dst[1] = a1; dst[2] = a2;
    }
}

// ---------------------------------------------------------------------------
// Vertical blur, all 4 levels per block; writes one full 32B record.
// ---------------------------------------------------------------------------
__global__ __launch_bounds__(128)
void blur_v4(const float* __restrict__ tmp, float4* __restrict__ blurp,
             const float* __restrict__ wts) {
    __shared__ float wS[4][32];
    int bid  = blockIdx.x;
    int yrow = bid & 127;
    int face = bid >> 7;
    int tid  = threadIdx.x;

    wS[tid >> 5][tid & 31] = wts[tid];
    __syncthreads();

    int x = tid;
    H8U ra, rb;
#pragma unroll
    for (int lvl = 0; lvl < 4; ++lvl) {
        const float* base = tmp + (size_t)(lvl * 6 + face) * 128 * 128 * 3;
        float a0 = 0.f, a1 = 0.f, a2 = 0.f;
        for (int t = 0; t < KSIZE; ++t) {
            int yy = yrow + t - HRAD;
            if (yy >= 0 && yy < 128) {
                float w = wS[lvl][t];
                const float* p = base + (size_t)(yy * 128 + x) * 3;
                a0 += w * p[0];
                a1 += w * p[1];
                a2 += w * p[2];
            }
        }
        H8U& r = (lvl < 2) ? ra : rb;
        int off = (lvl & 1) * 4;
        r.h[off + 0] = __float2half(a0);
        r.h[off + 1] = __float2half(a1);
        r.h[off + 2] = __float2half(a2);
        r.h[off + 3] = __float2half(0.0f);
    }
    int rec = ((face * 64 + (yrow >> 1)) * 128 + x) * 2 + (yrow & 1);
    blurp[rec * 2 + 0] = ra.f4;
    blurp[rec * 2 + 1] = rb.f4;
}

// ---------------------------------------------------------------------------
// Per-ray shading body
// ---------------------------------------------------------------------------
__device__ inline void shade_one(float x, float y, float z, float sa,
                                 const float2* __restrict__ bg0p,
                                 const float2* __restrict__ bg1p,
                                 const float4* __restrict__ blurp,
                                 float* __restrict__ R) {
    int face; float u, v;
    cube_coords(x, y, z, face, u, v);

    const float saTexel = (float)(4.0 * M_PI / (6.0 * 512.0 * 512.0));
    float m = logf(sa / saTexel);
    m = m / 1.3862943611198906f;   // f32(log(4))
    m = m * 0.5f;
    m = fminf(fmaxf(m, 0.0f), 3.0f);

    if (m >= 2.0f) {
        BLR b = bl_rec(u, v, face);
        H8U q00a, q00b, q10a, q10b, q01a, q01b, q11a, q11b;
        q00a.f4 = blurp[b.r00 * 2 + 0]; q00b.f4 = blurp[b.r00 * 2 + 1];
        q10a.f4 = blurp[b.r10 * 2 + 0]; q10b.f4 = blurp[b.r10 * 2 + 1];
        q01a.f4 = blurp[b.r01 * 2 + 0]; q01b.f4 = blurp[b.r01 * 2 + 1];
        q11a.f4 = blurp[b.r11 * 2 + 0]; q11b.f4 = blurp[b.r11 * 2 + 1];

        float w0 = 1.0f - fminf(fabsf(3.0f - m), 1.0f);
        float w1 = 1.0f - fminf(fabsf(2.5f - m), 1.0f);
        float w2 = 1.0f - fminf(fabsf(2.0f - m), 1.0f);
        float w3 = 1.0f - fminf(fabsf(1.5f - m), 1.0f);

        float b0 = 0.f, b1 = 0.f, b2 = 0.f;
        accum_level(q00a, q10a, q01a, q11a, 0, w0, b.wx, b.wy, b0, b1, b2);
        accum_level(q00a, q10a, q01a, q11a, 4, w1, b.wx, b.wy, b0, b1, b2);
        accum_level(q00b, q10b, q01b, q11b, 0, w2, b.wx, b.wy, b0, b1, b2);
        accum_level(q00b, q10b, q01b, q11b, 4, w3, b.wx, b.wy, b0, b1, b2);

        float denom = fmaxf(w0 + w1 + w2 + w3, 1e-8f);
        R[0] = b0 / denom; R[1] = b1 / denom; R[2] = b2 / denom;
    } else {
        BLT b128 = bl_tiled(u, v, 128, 128, face);
        BLT b512 = bl_tiled(u, v, 512, 512, face);
        float c0[3], c1[3];
        fetch_bl(bg0p, b128, c0);
        fetch_bl(bg1p, b512, c1);
        R[0] = c0[0] + 0.5f * c1[0];
        R[1] = c0[1] + 0.5f * c1[1];
        R[2] = c0[2] + 0.5f * c1[2];
    }
}

// ---------------------------------------------------------------------------
// Shade: 4 rays per thread, fully vectorized stream I/O.
// ---------------------------------------------------------------------------
__global__ __launch_bounds__(256)
void shade4(const float4* __restrict__ vd4, const float4* __restrict__ sa4,
            const float2* __restrict__ bg0p, const float2* __restrict__ bg1p,
            const float4* __restrict__ blurp, float4* __restrict__ out4,
            int nquads) {
    int q = blockIdx.x * blockDim.x + threadIdx.x;
    if (q >= nquads) return;

    float4 a = vd4[3 * q + 0];
    float4 b = vd4[3 * q + 1];
    float4 c = vd4[3 * q + 2];
    float4 s = sa4[q];

    float X[4] = {a.x, a.w, b.z, c.y};
    float Y[4] = {a.y, b.x, b.w, c.z};
    float Z[4] = {a.z, b.y, c.x, c.w};
    float S[4] = {s.x, s.y, s.z, s.w};

    float R[12];
#pragma unroll
    for (int r = 0; r < 4; ++r) {
        shade_one(X[r], Y[r], Z[r], S[r], bg0p, bg1p, blurp, &R[3 * r]);
    }

    out4[3 * q + 0] = make_float4(R[0], R[1], R[2],  R[3]);
    out4[3 * q + 1] = make_float4(R[4], R[5], R[6],  R[7]);
    out4[3 * q + 2] = make_float4(R[8], R[9], R[10], R[11]);
}

// ---------------------------------------------------------------------------
extern "C" void kernel_launch(void* const* d_in, const int* in_sizes, int n_in,
                              void* d_out, int out_size, void* d_ws, size_t ws_size,
                              hipStream_t stream) {
    const float* viewdirs = (const float*)d_in[0];   // (B,3)
    const float* saSample = (const float*)d_in[1];   // (B,1)
    const float* bg0      = (const float*)d_in[2];   // (6,128,128,3)
    const float* bg1      = (const float*)d_in[3];   // (6,512,512,3)
    float* out = (float*)d_out;

    int B = in_sizes[0] / 3;

    // ws layout:
    //   blurp : 196608 float4  (3.0 MB)
    //   bg0p  : 98304 float2   (0.79 MB)
    //   bg1p  : 1572864 float2 (12.6 MB)
    //   tmp   : 1179648 float  (4.7 MB)
    //   wts   : 128 float
    float4* blurp = (float4*)d_ws;
    float2* bg0p  = (float2*)(blurp + 196608);
    float2* bg1p  = bg0p + 98304;
    float*  tmp   = (float*)(bg1p + 1572864);
    float*  wts   = tmp + 1179648;

    init_weights<<<1, 128, 0, stream>>>(wts);

    int t0 = 6 * 128 * 128;
    int t1 = 6 * 512 * 512;
    pack_tiled<<<(t0 + 255) / 256, 256, 0, stream>>>(bg0, bg0p, 128, 128, t0);
    pack_tiled<<<(t1 + 255) / 256, 256, 0, stream>>>(bg1, bg1p, 512, 512, t1);

    blur_h4<<<6 * 128, 128, 0, stream>>>(bg0, tmp, wts);
    blur_v4<<<6 * 128, 128, 0, stream>>>(tmp, blurp, wts);

    int nquads = B / 4;   // B = 2097152, divisible by 4
    int threads = 256;
    int blocks = (nquads + threads - 1) / threads;
    shade4<<<blocks, threads, 0, stream>>>((const float4*)viewdirs,
                                           (const float4*)saSample,
                                           bg0p, bg1p, blurp,
                                           (float4*)out, nquads);
}